// Round 5
// baseline (340.846 us; speedup 1.0000x reference)
//
#include <hip/hip_runtime.h>

// ---------- types ----------
using bf16x8 = __attribute__((ext_vector_type(8))) short;           // 8 bf16 (4 VGPR)
using u16x8  = __attribute__((ext_vector_type(8))) unsigned short;  // 16B staging
using u32x4  = __attribute__((ext_vector_type(4))) unsigned int;
using f32x4  = __attribute__((ext_vector_type(4))) float;
using f32x16 = __attribute__((ext_vector_type(16))) float;
using f32x4v = __attribute__((ext_vector_type(4))) float;

__device__ inline unsigned short f2bf(float f) {
  unsigned int u = __builtin_bit_cast(unsigned int, f);
  return (unsigned short)((u + 0x7fffu + ((u >> 16) & 1u)) >> 16);  // RNE
}

#define MFMA16(a, b, c) __builtin_amdgcn_mfma_f32_16x16x32_bf16((a), (b), (c), 0, 0, 0)
#define MFMA32(a, b, c) __builtin_amdgcn_mfma_f32_32x32x16_bf16((a), (b), (c), 0, 0, 0)

// LDS-visibility-only barrier: drains lgkmcnt but NOT vmcnt, so register-
// destined global prefetches stay in flight across the sync (v3-proven).
__device__ __forceinline__ void lds_barrier() {
  __builtin_amdgcn_sched_barrier(0);
  asm volatile("s_waitcnt lgkmcnt(0)" ::: "memory");
  __builtin_amdgcn_sched_barrier(0);
  __builtin_amdgcn_s_barrier();
  __builtin_amdgcn_sched_barrier(0);
}

// pack two f32 -> one u32 of 2 bf16 (RNE), single VOP3
__device__ __forceinline__ unsigned int cvtpk(float lo, float hi) {
  unsigned int r;
  asm("v_cvt_pk_bf16_f32 %0, %1, %2" : "=v"(r) : "v"(lo), "v"(hi));
  return r;
}
// swap a's high 32 lanes with b's low 32 lanes (gfx950)
__device__ __forceinline__ void plswap(unsigned int& a, unsigned int& b) {
  asm volatile("v_permlane32_swap_b32 %0, %1" : "+v"(a), "+v"(b));
}

// Problem constants
#define LL 4096
#define NB 4
#define DD 512
#define KDIM 128

// ==========================================================================
// proj_qk (merged q+k): Out[b][l][128] = bf16( scale * l2norm( X @ Wk^T + bk ) )
// Query output is pre-scaled by 30*log2(e) so attn softmax is p=exp2(S).
// ==========================================================================
__global__ __launch_bounds__(256) void proj_qk_kernel(
    const float* __restrict__ Xq, const float* __restrict__ Xk,
    const float* __restrict__ Wk, const float* __restrict__ bk,
    unsigned short* __restrict__ Outq, unsigned short* __restrict__ Outk)
{
  __shared__ char smem[49152];                       // Xs 16KB | Ws 32KB
  char* Xs = smem;
  char* Ws = smem + 16384;

  const int tid = threadIdx.x;
  const int w = tid >> 6, lane = tid & 63, lr = lane & 15, g = lane >> 4;
  const int sel = blockIdx.x & 1;
  const float* X = sel ? Xk : Xq;
  unsigned short* Out = sel ? Outk : Outq;
  const float scale = sel ? 1.0f : 43.2808512266689f;   // 30*log2(e)
  const int r0 = (blockIdx.x >> 1) * 64;

  f32x4 acc[8];
  #pragma unroll
  for (int nt = 0; nt < 8; ++nt) acc[nt] = f32x4{0.f, 0.f, 0.f, 0.f};

  for (int kc = 0; kc < 4; ++kc) {                   // K chunks of 128
    if (kc) __syncthreads();
    #pragma unroll
    for (int p = 0; p < 4; ++p) {
      int j = tid + p * 256;
      int row = j >> 4, e0 = (j & 15) * 8;
      const float* src = X + (size_t)(r0 + row) * DD + kc * 128 + e0;
      f32x4v f0 = *reinterpret_cast<const f32x4v*>(src);
      f32x4v f1 = *reinterpret_cast<const f32x4v*>(src + 4);
      u16x8 v;
      #pragma unroll
      for (int e = 0; e < 4; ++e) { v[e] = f2bf(f0[e]); v[e + 4] = f2bf(f1[e]); }
      *reinterpret_cast<u16x8*>(Xs + row * 256 + ((e0 * 2) ^ ((row & 7) << 4))) = v;
    }
    #pragma unroll
    for (int p = 0; p < 8; ++p) {
      int j = tid + p * 256;
      int n = j >> 4, e0 = (j & 15) * 8;
      const float* src = Wk + (size_t)n * DD + kc * 128 + e0;
      f32x4v f0 = *reinterpret_cast<const f32x4v*>(src);
      f32x4v f1 = *reinterpret_cast<const f32x4v*>(src + 4);
      u16x8 v;
      #pragma unroll
      for (int e = 0; e < 4; ++e) { v[e] = f2bf(f0[e]); v[e + 4] = f2bf(f1[e]); }
      *reinterpret_cast<u16x8*>(Ws + n * 256 + ((e0 * 2) ^ ((n & 7) << 4))) = v;
    }
    __syncthreads();
    const int arow = w * 16 + lr;
    #pragma unroll
    for (int ks = 0; ks < 4; ++ks) {
      int oa = (ks * 64 + g * 16) ^ ((arow & 7) << 4);
      bf16x8 a = *reinterpret_cast<const bf16x8*>(Xs + arow * 256 + oa);
      #pragma unroll
      for (int nt = 0; nt < 8; ++nt) {
        int n = nt * 16 + lr;
        int ob = (ks * 64 + g * 16) ^ ((n & 7) << 4);
        bf16x8 bb = *reinterpret_cast<const bf16x8*>(Ws + n * 256 + ob);
        acc[nt] = MFMA16(a, bb, acc[nt]);
      }
    }
  }

  float bias[8];
  #pragma unroll
  for (int nt = 0; nt < 8; ++nt) bias[nt] = bk[nt * 16 + lr];
  #pragma unroll
  for (int nt = 0; nt < 8; ++nt)
    #pragma unroll
    for (int i = 0; i < 4; ++i) acc[nt][i] += bias[nt];

  f32x4 ss = f32x4{0.f, 0.f, 0.f, 0.f};
  #pragma unroll
  for (int nt = 0; nt < 8; ++nt)
    #pragma unroll
    for (int i = 0; i < 4; ++i) ss[i] += acc[nt][i] * acc[nt][i];
  #pragma unroll
  for (int m = 1; m < 16; m <<= 1) {
    #pragma unroll
    for (int i = 0; i < 4; ++i) ss[i] += __shfl_xor(ss[i], m);
  }
  float inv[4];
  #pragma unroll
  for (int i = 0; i < 4; ++i) inv[i] = scale / fmaxf(sqrtf(ss[i]), 1e-12f);

  #pragma unroll
  for (int nt = 0; nt < 8; ++nt) {
    int c = nt * 16 + lr;
    #pragma unroll
    for (int i = 0; i < 4; ++i) {
      int r = r0 + w * 16 + g * 4 + i;
      int l = r >> 2, b = r & 3;
      Out[((size_t)(b * LL + l)) * KDIM + c] = f2bf(acc[nt][i] * inv[i]);
    }
  }
}

// ==========================================================================
// proj_v: Vt[b][d][s] = bf16( value[s][b][:] @ Wv^T + bv )   (transposed store)
// ==========================================================================
__global__ __launch_bounds__(256) void proj_v_kernel(
    const float* __restrict__ X, const float* __restrict__ Wv,
    const float* __restrict__ bv, unsigned short* __restrict__ VtOut)
{
  __shared__ char smem[40960];
  char* Xs = smem;
  char* Ws = smem + 32768;

  const int tid = threadIdx.x;
  const int w = tid >> 6, lane = tid & 63, lr = lane & 15, g = lane >> 4;
  const int rb = blockIdx.x >> 3, nb = blockIdx.x & 7;
  const int r0 = rb * 256, d0 = nb * 64;

  f32x4 acc[4][4];
  #pragma unroll
  for (int rt = 0; rt < 4; ++rt)
    #pragma unroll
    for (int nt = 0; nt < 4; ++nt) acc[rt][nt] = f32x4{0.f, 0.f, 0.f, 0.f};

  for (int kc = 0; kc < 8; ++kc) {
    if (kc) __syncthreads();
    #pragma unroll
    for (int p = 0; p < 8; ++p) {
      int j = tid + p * 256;
      int row = j >> 3, e0 = (j & 7) * 8;
      const float* src = X + (size_t)(r0 + row) * DD + kc * 64 + e0;
      f32x4v f0 = *reinterpret_cast<const f32x4v*>(src);
      f32x4v f1 = *reinterpret_cast<const f32x4v*>(src + 4);
      u16x8 v;
      #pragma unroll
      for (int e = 0; e < 4; ++e) { v[e] = f2bf(f0[e]); v[e + 4] = f2bf(f1[e]); }
      *reinterpret_cast<u16x8*>(Xs + row * 128 + ((e0 * 2) ^ ((row & 7) << 4))) = v;
    }
    #pragma unroll
    for (int p = 0; p < 2; ++p) {
      int j = tid + p * 256;
      int n = j >> 3, e0 = (j & 7) * 8;
      const float* src = Wv + (size_t)(d0 + n) * DD + kc * 64 + e0;
      f32x4v f0 = *reinterpret_cast<const f32x4v*>(src);
      f32x4v f1 = *reinterpret_cast<const f32x4v*>(src + 4);
      u16x8 v;
      #pragma unroll
      for (int e = 0; e < 4; ++e) { v[e] = f2bf(f0[e]); v[e + 4] = f2bf(f1[e]); }
      *reinterpret_cast<u16x8*>(Ws + n * 128 + ((e0 * 2) ^ ((n & 7) << 4))) = v;
    }
    __syncthreads();
    #pragma unroll
    for (int ks = 0; ks < 2; ++ks) {
      bf16x8 a[4];
      #pragma unroll
      for (int rt = 0; rt < 4; ++rt) {
        int arow = w * 64 + rt * 16 + lr;
        a[rt] = *reinterpret_cast<const bf16x8*>(
            Xs + arow * 128 + ((ks * 64 + g * 16) ^ ((arow & 7) << 4)));
      }
      #pragma unroll
      for (int nt = 0; nt < 4; ++nt) {
        int n = nt * 16 + lr;
        bf16x8 bb = *reinterpret_cast<const bf16x8*>(
            Ws + n * 128 + ((ks * 64 + g * 16) ^ ((n & 7) << 4)));
        #pragma unroll
        for (int rt = 0; rt < 4; ++rt) acc[rt][nt] = MFMA16(a[rt], bb, acc[rt][nt]);
      }
    }
  }

  __syncthreads();
  float bias[4];
  #pragma unroll
  for (int nt = 0; nt < 4; ++nt) bias[nt] = bv[d0 + nt * 16 + lr];

  unsigned short* Ts = (unsigned short*)smem;
  #pragma unroll
  for (int rt = 0; rt < 4; ++rt)
    #pragma unroll
    for (int nt = 0; nt < 4; ++nt) {
      int dl = nt * 16 + lr;
      #pragma unroll
      for (int i = 0; i < 4; ++i) {
        int rl = w * 64 + rt * 16 + g * 4 + i;
        Ts[dl * 256 + (rl ^ ((dl & 31) << 1))] = f2bf(acc[rt][nt][i] + bias[nt]);
      }
    }
  __syncthreads();

  int bsel = tid >> 6, dl = tid & 63;
  int l0 = r0 >> 2;
  #pragma unroll
  for (int jj = 0; jj < 8; ++jj) {
    u16x8 v;
    #pragma unroll
    for (int e = 0; e < 8; ++e) {
      int rl = (jj * 8 + e) * 4 + bsel;
      v[e] = Ts[dl * 256 + (rl ^ ((dl & 31) << 1))];
    }
    *reinterpret_cast<u16x8*>(VtOut + ((size_t)(bsel * DD + d0 + dl)) * LL + l0 + jj * 8) = v;
  }
}

// ==========================================================================
// attn v5: swapped QK^T + in-register softmax (T12), no P in LDS.
// Block = 256 thr / 4 waves; wave w owns (32 q-rows) x (d-slice [w*128,+128)).
// grid 512 = 4 b x 128 qtiles -> 2 independent blocks/CU (phase-offset).
// QK^T recomputed per d-slice wave (x4 MFMA redundancy, zero extra traffic).
// K tile [64 s][128 k] double-buffered in LDS, XOR-swizzled (row&7)<<4,
// reg-staged; only barrier = K buffer recycle (lgkm-only, loads span it).
// V B-fragments straight from global (64B/row/step fully used).
// S^T = mfma32(A=K, B=Q): col=lane&31=q, row s=crow(r,hi) [verified m74/m101].
// P -> PV A-frags via v_cvt_pk_bf16_f32 + v_permlane32_swap_b32.
// ==========================================================================
#define KVB 64
#define NSTEP (LL / KVB)          // 64

__global__ __launch_bounds__(256, 2) void attn_kernel(
    const unsigned short* __restrict__ Qn, const unsigned short* __restrict__ Kn,
    const unsigned short* __restrict__ Vt, float* __restrict__ Out)
{
  __shared__ char smem[32768];     // K dbuf: 2 x [64][256B]

  const int tid = threadIdx.x;
  const int w = tid >> 6, lane = tid & 63;
  const int l5 = lane & 31, hi = lane >> 5;
  const int slot = tid & 15, rg = tid >> 4;    // staging: 16B slot, 4 rows/thread

  // XCD-grouping swizzle: batch b -> XCD pair {2b,2b+1} (rr dispatch heuristic)
  const int bid = blockIdx.x;
  const int b = (bid & 7) >> 1;
  const int qt = ((bid >> 3) << 1) | (bid & 1);   // 0..127
  const int q0 = qt * 32;

  const unsigned short* Kp = Kn + (size_t)b * LL * KDIM;
  const unsigned short* Vp = Vt + ((size_t)b * DD + w * 128) * LL;

  // Q B-fragments: q = q0 + l5, k = kc*16 + hi*8 (+e). 8 frags = 32 VGPR.
  bf16x8 qf[8];
  {
    const unsigned short* qp = Qn + ((size_t)(b * LL + q0 + l5)) * KDIM + hi * 8;
    #pragma unroll
    for (int kc = 0; kc < 8; ++kc)
      qf[kc] = *reinterpret_cast<const bf16x8*>(qp + kc * 16);
  }

  f32x16 acc[4];
  #pragma unroll
  for (int dt = 0; dt < 4; ++dt)
    #pragma unroll
    for (int r = 0; r < 16; ++r) acc[dt][r] = 0.f;
  float lsum = 0.f;

  // ---- prologue: stage K(0) -> buf0 ----
  {
    const unsigned short* src = Kp + (size_t)(rg * 4) * KDIM + slot * 8;
    #pragma unroll
    for (int i = 0; i < 4; ++i) {
      u16x8 v = *reinterpret_cast<const u16x8*>(src + i * KDIM);
      int row = rg * 4 + i;
      *reinterpret_cast<u16x8*>(smem + row * 256 + ((slot * 16) ^ ((row & 7) << 4))) = v;
    }
  }
  __syncthreads();

  for (int t = 0; t < NSTEP; ++t) {
    char* kcur = smem + (t & 1) * 16384;
    char* knxt = smem + ((t + 1) & 1) * 16384;
    const int tn = (t + 1 < NSTEP) ? t + 1 : t;
    const int s0 = t * KVB;

    // ---- issue K(t+1) stage loads first (oldest vmcnt; span the barrier) ----
    u16x8 kst[4];
    {
      const unsigned short* src = Kp + ((size_t)(tn * KVB + rg * 4)) * KDIM + slot * 8;
      #pragma unroll
      for (int i = 0; i < 4; ++i)
        kst[i] = *reinterpret_cast<const u16x8*>(src + i * KDIM);
    }

    #pragma unroll
    for (int sub = 0; sub < 2; ++sub) {
      // ---- V B-fragments for this 32-s subtile (consumed at PV below) ----
      bf16x8 vf[4][2];
      #pragma unroll
      for (int dt = 0; dt < 4; ++dt)
        #pragma unroll
        for (int sh = 0; sh < 2; ++sh)
          vf[dt][sh] = *reinterpret_cast<const bf16x8*>(
              Vp + (size_t)(dt * 32 + l5) * LL + s0 + sub * 32 + sh * 16 + hi * 8);

      // ---- swapped QK^T: S^T[s][q], A=K from LDS, B=Q regs ----
      const int row = sub * 32 + l5;
      const char* kb = kcur + row * 256;
      const int sw = (row & 7) << 4;
      f32x16 sacc;
      #pragma unroll
      for (int r = 0; r < 16; ++r) sacc[r] = 0.f;
      __builtin_amdgcn_s_setprio(1);
      #pragma unroll
      for (int kc = 0; kc < 8; ++kc) {
        bf16x8 kf = *reinterpret_cast<const bf16x8*>(kb + ((kc * 32 + hi * 16) ^ sw));
        sacc = MFMA32(kf, qf[kc], sacc);
      }
      __builtin_amdgcn_s_setprio(0);

      // ---- softmax numerator in-register: p = exp2(S) (Q pre-scaled) ----
      float p[16];
      #pragma unroll
      for (int r = 0; r < 16; ++r) p[r] = exp2f(sacc[r]);
      #pragma unroll
      for (int r = 0; r < 16; ++r) lsum += p[r];

      // ---- pack P -> PV A-fragments (cvt_pk + permlane32_swap) ----
      unsigned int w0 = cvtpk(p[0], p[1]),   w2 = cvtpk(p[4], p[5]);
      unsigned int w1 = cvtpk(p[2], p[3]),   w3 = cvtpk(p[6], p[7]);
      plswap(w0, w2);  plswap(w1, w3);
      unsigned int w4 = cvtpk(p[8], p[9]),   w6 = cvtpk(p[12], p[13]);
      unsigned int w5 = cvtpk(p[10], p[11]), w7 = cvtpk(p[14], p[15]);
      plswap(w4, w6);  plswap(w5, w7);
      bf16x8 pa0 = __builtin_bit_cast(bf16x8, u32x4{w0, w1, w2, w3});
      bf16x8 pa1 = __builtin_bit_cast(bf16x8, u32x4{w4, w5, w6, w7});

      // ---- PV: acc[dt] += P^T(32q x 32s) * V(32s x 32d per tile) ----
      __builtin_amdgcn_s_setprio(1);
      #pragma unroll
      for (int dt = 0; dt < 4; ++dt) acc[dt] = MFMA32(pa0, vf[dt][0], acc[dt]);
      #pragma unroll
      for (int dt = 0; dt < 4; ++dt) acc[dt] = MFMA32(pa1, vf[dt][1], acc[dt]);
      __builtin_amdgcn_s_setprio(0);
    }

    // ---- write staged K(t+1) regs -> other buffer (auto counted vmcnt) ----
    #pragma unroll
    for (int i = 0; i < 4; ++i) {
      int row = rg * 4 + i;
      *reinterpret_cast<u16x8*>(knxt + row * 256 + ((slot * 16) ^ ((row & 7) << 4))) = kst[i];
    }
    lds_barrier();   // lgkm-only: K buffers safe, global loads stay in flight
  }

  // ---- epilogue: combine half-row sums, scale, store ----
  float ltot = lsum + __shfl_xor(lsum, 32);
  #pragma unroll
  for (int r = 0; r < 16; ++r) {
    const int crow = (r & 3) + 8 * (r >> 2) + 4 * hi;   // q-row of acc elem r
    float ls = __shfl(ltot, crow);                       // lane crow holds q=crow
    float linv = 1.0f / ls;
    size_t o = ((size_t)(q0 + crow) * NB + b) * DD + w * 128 + l5;
    #pragma unroll
    for (int dt = 0; dt < 4; ++dt)
      Out[o + dt * 32] = acc[dt][r] * linv;
  }
}

// ==========================================================================
extern "C" void kernel_launch(void* const* d_in, const int* in_sizes, int n_in,
                              void* d_out, int out_size, void* d_ws, size_t ws_size,
                              hipStream_t stream) {
  const float* query = (const float*)d_in[0];
  const float* key   = (const float*)d_in[1];
  const float* value = (const float*)d_in[2];
  const float* WKw   = (const float*)d_in[3];
  const float* WKb   = (const float*)d_in[4];
  const float* WVw   = (const float*)d_in[5];
  const float* WVb   = (const float*)d_in[6];
  float* out = (float*)d_out;

  unsigned short* wqn = (unsigned short*)d_ws;            // [4][4096][128] bf16 (pre-scaled)
  unsigned short* wkn = wqn + (size_t)NB * LL * KDIM;     // [4][4096][128] bf16
  unsigned short* vt  = wkn + (size_t)NB * LL * KDIM;     // [4][512][4096] bf16

  proj_qk_kernel<<<512, 256, 0, stream>>>(query, key, WKw, WKb, wqn, wkn);
  proj_v_kernel <<<512, 256, 0, stream>>>(value, WVw, WVb, vt);
  attn_kernel   <<<512, 256, 0, stream>>>(wqn, wkn, vt, out);
}